// Round 14
// baseline (1396.507 us; speedup 1.0000x reference)
//
#include <hip/hip_runtime.h>

#define T_STEPS 3
#define NB 2
#define H_LO 360
#define W_LO 640
#define H_HI 720
#define W_HI 1280
#define HW_LO (H_LO*W_LO)
#define HW_HI (H_HI*W_HI)
#define TILE 12

typedef _Float16 f16;
typedef __attribute__((ext_vector_type(4))) _Float16 f16x4;
typedef __attribute__((ext_vector_type(8))) _Float16 f16x8;
typedef __attribute__((ext_vector_type(4))) float f32x4;

// LDS map (total 37952 B -> 3 blocks/CU at bound-3):
//  h1 f16 [16][16][64 swz]  @0      32768 B
//  h2 f16 [14][14][64 swz]  @0      25088 B (ALIASES h1; h1 dead after conv2 MFMAs + barrier)
//  cnn_in f16 [18][18][8]   @32768   5184 B (dead after conv1)
//  res f32 [2][144]         @32768   1152 B (aliases cnn; written in conv3 epilogue)
#define OFF_H1  0
#define OFF_H2  0
#define OFF_CNN 32768
#define OFF_RES 32768
#define LDS_BYTES 37952

__device__ __forceinline__ int imin(int a,int b){return a<b?a:b;}
__device__ __forceinline__ int imax(int a,int b){return a>b?a:b;}
__device__ __forceinline__ int iclamp(int v,int lo,int hi){return imin(imax(v,lo),hi);}

__device__ __forceinline__ float depth_tx(float d0){
  float d = 10.0f / (100.0f - d0*99.9f);
  return (d - 0.1f) / 99.9f;
}

__device__ __forceinline__ void cubw(float t, float* w){
  const float a = -0.75f;
  float t2 = t*t, t3 = t2*t;
  w[0] = a*(t3 - 2.0f*t2 + t);
  w[1] = (a+2.0f)*t3 - (a+3.0f)*t2 + 1.0f;
  float s = 1.0f - t;
  w[2] = (a+2.0f)*s*s*s - (a+3.0f)*s*s + 1.0f;
  float u = 2.0f - t;
  w[3] = a*u*u*u - 5.0f*a*u*u + 8.0f*a*u - 4.0f*a;
}

// jitter-aligned bicubic upsample of [frame rgb, depth_tx] at hi-res pixel (x,y)
__device__ __forceinline__ float4 fb_bicubic(const float* __restrict__ fbase,
    const float* __restrict__ dbase, float jx, float jy, int x, int y){
  float gx = (2.0f*(float)x + 1.0f)/(float)W_HI - 1.0f + 2.0f*(0.5f - jx)/(float)W_LO;
  float gy = (2.0f*(float)y + 1.0f)/(float)H_HI - 1.0f + 2.0f*(0.5f - jy)/(float)H_LO;
  float ix = ((gx + 1.0f)*(float)W_LO - 1.0f)*0.5f;
  float iy = ((gy + 1.0f)*(float)H_LO - 1.0f)*0.5f;
  float xf = floorf(ix), yf = floorf(iy);
  float tx = ix - xf, ty = iy - yf;
  int xi = (int)xf, yi = (int)yf;
  float wx[4], wy[4]; cubw(tx, wx); cubw(ty, wy);
  int xs[4], ys[4];
  #pragma unroll
  for (int j=0;j<4;j++){ xs[j]=iclamp(xi-1+j,0,W_LO-1); ys[j]=iclamp(yi-1+j,0,H_LO-1); }
  float a0=0.f,a1=0.f,a2=0.f,a3=0.f;
  #pragma unroll
  for (int i=0;i<4;i++){
    #pragma unroll
    for (int j=0;j<4;j++){
      float wgt = wy[i]*wx[j];
      int off = ys[i]*W_LO + xs[j];
      a0 += wgt*fbase[off];
      a1 += wgt*fbase[HW_LO+off];
      a2 += wgt*fbase[2*HW_LO+off];
      a3 += wgt*depth_tx(dbase[off]);
    }
  }
  return make_float4(a0,a1,a2,a3);
}

// ---------------- weight prep (EXACT R10 layout): f32 -> f16, relayout + XOR-swizzle ----------------
// wbuf f16: [0,8192) w1 [oc64][kk128]; [8192,45056) w2 [oc64][kk576]; [45056,46208) w3 [2][576]; pad to 46592
__global__ __launch_bounds__(256) void k_wprep(const float* __restrict__ w1g,
    const float* __restrict__ w2g, const float* __restrict__ w3g, f16* __restrict__ wbuf){
  int i = blockIdx.x*256 + threadIdx.x;
  if (i >= 46592) return;
  float val = 0.0f;
  if (i < 8192){
    int oc = i>>7, kk = i&127, k = kk ^ ((oc&7)<<3);      // k = tap*8+ic, pad [72,128)=0
    if (k < 72) val = w1g[(oc*8 + (k&7))*9 + (k>>3)];
  } else if (i < 45056){
    int j = i - 8192; int oc = j/576, kk = j - oc*576, k = kk ^ ((oc&7)<<3); // k = tap*64+ic
    val = w2g[(oc*64 + (k&63))*9 + (k>>6)];
  } else {
    int j = i - 45056;
    if (j < 1152){ int nn = j/576, k = j - nn*576;
      val = w3g[(nn*64 + (k&63))*9 + (k>>6)];
    }
  }
  wbuf[i] = (f16)val;
}

// ---------------- k_pw: FB4 = bicubic prep (always); histB = mv-warp of histA, OOB -> FB (if doWarp) ----------------
__global__ __launch_bounds__(256) void k_pw(const float4* __restrict__ histA,
    const float* __restrict__ mv, const float* __restrict__ frame,
    const float* __restrict__ depth, const float* __restrict__ jit,
    float4* __restrict__ FB, float4* __restrict__ histB, int doWarp){
  int idx = blockIdx.x*256 + threadIdx.x;
  if (idx >= NB*HW_HI) return;
  int n = idx / HW_HI, p = idx - n*HW_HI;
  int y = p / W_HI, x = p - y*W_HI;
  const float* fbase = frame + (size_t)n*3*HW_LO;
  const float* dbase = depth + (size_t)n*HW_LO;
  float4 fb4 = fb_bicubic(fbase, dbase, jit[n*2], jit[n*2+1], x, y);
  FB[(size_t)n*HW_HI + p] = fb4;
  if (!doWarp) return;

  float cy = fmaxf(((float)y + 0.5f)/2.0f - 0.5f, 0.0f);
  float cx = fmaxf(((float)x + 0.5f)/2.0f - 0.5f, 0.0f);
  float y0f = floorf(cy), x0f = floorf(cx);
  float tyv = cy - y0f, txv = cx - x0f;
  int y0 = iclamp((int)y0f, 0, H_LO-1), y1 = iclamp((int)y0f+1, 0, H_LO-1);
  int x0 = iclamp((int)x0f, 0, W_LO-1), x1 = iclamp((int)x0f+1, 0, W_LO-1);
  const float* mb = mv + (size_t)n*HW_LO*2;
  float gx, gy;
  {
    float v00 = mb[(y0*W_LO+x0)*2], v01 = mb[(y0*W_LO+x1)*2];
    float v10 = mb[(y1*W_LO+x0)*2], v11 = mb[(y1*W_LO+x1)*2];
    float r0 = v00*(1.0f-tyv) + v10*tyv;
    float r1 = v01*(1.0f-tyv) + v11*tyv;
    gx = r0*(1.0f-txv) + r1*txv;
  }
  {
    float v00 = mb[(y0*W_LO+x0)*2+1], v01 = mb[(y0*W_LO+x1)*2+1];
    float v10 = mb[(y1*W_LO+x0)*2+1], v11 = mb[(y1*W_LO+x1)*2+1];
    float r0 = v00*(1.0f-tyv) + v10*tyv;
    float r1 = v01*(1.0f-tyv) + v11*tyv;
    gy = r0*(1.0f-txv) + r1*txv;
  }
  bool oob = (gx > 1.0f) || (gx < -1.0f) || (gy > 1.0f) || (gy < -1.0f);
  float4 res;
  if (oob) {
    res = fb4;   // same value as FB[n*HW+p] just computed
  } else {
    const float4* hb = histA + (size_t)n*HW_HI;
    float ix = ((gx + 1.0f)*(float)W_HI - 1.0f)*0.5f;
    float iy = ((gy + 1.0f)*(float)H_HI - 1.0f)*0.5f;
    float xf = floorf(ix), yf = floorf(iy);
    float tx = ix - xf, ty = iy - yf;
    int xi = (int)xf, yi = (int)yf;
    float wx[4], wy[4]; cubw(tx, wx); cubw(ty, wy);
    int xs[4], ys[4];
    #pragma unroll
    for (int j=0;j<4;j++){ xs[j]=iclamp(xi-1+j,0,W_HI-1); ys[j]=iclamp(yi-1+j,0,H_HI-1); }
    float a0=0.f,a1=0.f,a2=0.f,a3=0.f;
    #pragma unroll
    for (int i=0;i<4;i++){
      #pragma unroll
      for (int j=0;j<4;j++){
        float wgt = wy[i]*wx[j];
        float4 v = hb[ys[i]*W_HI + xs[j]];
        a0 += wgt*v.x; a1 += wgt*v.y; a2 += wgt*v.z; a3 += wgt*v.w;
      }
    }
    res = make_float4(a0,a1,a2,a3);
  }
  histB[(size_t)n*HW_HI + p] = res;
}

// ---------------- fused conv1+conv2+conv3 (R13 + s_setprio around MFMA clusters) ----------------
__global__ __launch_bounds__(256,3) void k_fused(
    const float* __restrict__ frame, const float* __restrict__ depth,
    const float* __restrict__ jit, const float4* __restrict__ histIn,
    const float4* __restrict__ FB, const f16* __restrict__ wbuf,
    const float* __restrict__ b1g, const float* __restrict__ b2g, const float* __restrict__ b3g,
    float4* __restrict__ histOut, float* __restrict__ outp)
{
  __shared__ __attribute__((aligned(16))) char smem[LDS_BYTES];
  const int tid = threadIdx.x;
  const int wv = tid>>6, ln = tid&63, lr = ln&15, lq = ln>>4;
  const int n  = blockIdx.z;
  const int r0 = blockIdx.y * TILE;
  const int c0 = blockIdx.x * TILE;
  const float jx = jit[n*2], jy = jit[n*2+1];
  const int jix = (int)floorf(jx*2.0f), jiy = (int)floorf(jy*2.0f);
  const float* fbase = frame + (size_t)n*3*HW_LO;
  const float* dbase = depth + (size_t)n*HW_LO;
  const float4* hist4 = histIn + (size_t)n*HW_HI;
  const int wkk = (lr&7)<<3;     // weight k-swizzle key (oc&7 == lr&7)

  // prefetch conv1 weight fragments from global (latency hides under stage A)
  f16x8 B1[3][4];
  #pragma unroll
  for (int kc=0;kc<3;kc++)
    #pragma unroll
    for (int oct=0;oct<4;oct++){
      int oc = oct*16 + lr;
      int k0 = kc*32 + lq*8;
      B1[kc][oct] = *(const f16x8*)(wbuf + oc*128 + (k0 ^ wkk));
    }

  // ---- Stage A: cnn_in tile (18x18x8) ----
  for (int e=tid; e<324; e+=256){
    int u = e/18, v = e - u*18;
    int cgy = iclamp(r0-3+u, 0, H_HI-1);
    int cgx = iclamp(c0-3+v, 0, W_HI-1);
    float v0=0.f, v1=0.f, v2=0.f, v3=0.f;
    int yy = cgy - jiy, xx = cgx - jix;
    if (yy>=0 && xx>=0 && !(yy&1) && !(xx&1)){
      int off = (yy>>1)*W_LO + (xx>>1);
      v0 = fbase[off]; v1 = fbase[HW_LO+off]; v2 = fbase[2*HW_LO+off];
      v3 = depth_tx(dbase[off]);
    }
    float4 h = hist4[cgy*W_HI + cgx];
    f16x8 pk;
    pk[0]=(f16)v0; pk[1]=(f16)v1; pk[2]=(f16)v2; pk[3]=(f16)v3;
    pk[4]=(f16)h.x; pk[5]=(f16)h.y; pk[6]=(f16)h.z; pk[7]=(f16)h.w;
    *(f16x8*)(smem + OFF_CNN + e*16) = pk;
  }
  __syncthreads();

  // ---- conv1: D[oc][px] (weights as A-operand), M=oc 64, N=16 px/row, K=96 (pad of 72) ----
  {
    float4 b1v[4];
    #pragma unroll
    for (int oct=0;oct<4;oct++) b1v[oct] = *(const float4*)(b1g + oct*16 + lq*4);
    #pragma unroll
    for (int ty4=0;ty4<4;ty4++){
      int ty = wv*4 + ty4;
      int g1y = iclamp(r0-2+ty, 0, H_HI-1);
      int g1x = iclamp(c0-2+lr, 0, W_HI-1);
      f32x4 acc[4];
      #pragma unroll
      for (int oct=0;oct<4;oct++) acc[oct] = (f32x4){b1v[oct].x,b1v[oct].y,b1v[oct].z,b1v[oct].w};
      #pragma unroll
      for (int kc=0;kc<3;kc++){
        int k0 = kc*32 + lq*8;
        int t = imin(k0>>3, 8);
        int dy = (t*11)>>5; int dx = t - dy*3;
        int uu = iclamp(g1y+dy-1, 0, H_HI-1) - (r0-3);
        int vv = iclamp(g1x+dx-1, 0, W_HI-1) - (c0-3);
        f16x8 a = *(const f16x8*)(smem + OFF_CNN + (uu*18+vv)*16);
        __builtin_amdgcn_s_setprio(1);
        #pragma unroll
        for (int oct=0;oct<4;oct++)
          acc[oct] = __builtin_amdgcn_mfma_f32_16x16x32_f16(B1[kc][oct], a, acc[oct], 0,0,0);
        __builtin_amdgcn_s_setprio(0);
      }
      // h1 write (LDS swizzle): pixel = (ty, lr), oc = oct*16+lq*4+reg -> one f16x4 per oct
      #pragma unroll
      for (int oct=0;oct<4;oct++){
        f16x4 wv4;
        #pragma unroll
        for (int reg=0;reg<4;reg++) wv4[reg] = (f16)fmaxf(acc[oct][reg], 0.f);
        int oc0 = (oct*16 + lq*4) ^ ((lr&7)<<3);
        *(f16x4*)(smem + OFF_H1 + (((ty*16+lr)*64 + oc0)<<1)) = wv4;
      }
    }
  }
  __syncthreads();

  // ---- conv2: D[oc][m], M=oc 64, N=196 px (13 tiles), K=576; w2 from L2, next-kc prefetch ----
  {
    const int nmt = (wv==0) ? 4 : 3;
    const int mtid[4] = {wv, 4+wv, 8+wv, 12};
    int rowOf[4][3], colc[4][3][2];
    #pragma unroll
    for (int mti=0;mti<4;mti++){
      int m = imin(mtid[mti]*16 + lr, 195);
      int py = m/14, px = m - py*14;
      int Ay = iclamp(r0-1+py, 0, H_HI-1);
      int Ax = iclamp(c0-1+px, 0, W_HI-1);
      #pragma unroll
      for (int d=0;d<3;d++){
        rowOf[mti][d] = (iclamp(Ay+d-1, 0, H_HI-1) - (r0-2))*1024;  // *16*64
        int vv = iclamp(Ax+d-1, 0, W_HI-1) - (c0-2);
        int key = (vv&7)<<3;
        colc[mti][d][0] = vv*64 + ((lq*8) ^ key);
        colc[mti][d][1] = vv*64 + ((32+lq*8) ^ key);
      }
    }
    float4 b2v[4];
    #pragma unroll
    for (int oct=0;oct<4;oct++) b2v[oct] = *(const float4*)(b2g + oct*16 + lq*4);
    f32x4 acc2[4][4];
    #pragma unroll
    for (int mti=0;mti<4;mti++)
      #pragma unroll
      for (int oct=0;oct<4;oct++) acc2[mti][oct] = (f32x4){b2v[oct].x,b2v[oct].y,b2v[oct].z,b2v[oct].w};
    const f16* w2b = wbuf + 8192;   // [oc64][k576 swz]
    // prefetch kc=0 weight fragments
    f16x8 bf[4];
    #pragma unroll
    for (int oct=0;oct<4;oct++)
      bf[oct] = *(const f16x8*)(w2b + (oct*16+lr)*576 + ((lq*8) ^ wkk));
    #pragma unroll
    for (int kc=0;kc<18;kc++){
      const int tap = kc>>1, half = kc&1;
      const int dy = tap/3, dx = tap - dy*3;
      f16x8 bfn[4];
      if (kc < 17){
        const int kn = kc+1, tapn = kn>>1, halfn = kn&1;
        #pragma unroll
        for (int oct=0;oct<4;oct++)
          bfn[oct] = *(const f16x8*)(w2b + (oct*16+lr)*576 + ((tapn*64 + halfn*32 + lq*8) ^ wkk));
      }
      __builtin_amdgcn_s_setprio(1);
      #pragma unroll
      for (int mti=0;mti<4;mti++) if (mti < nmt){
        f16x8 a = *(const f16x8*)(smem + OFF_H1 + ((rowOf[mti][dy] + colc[mti][dx][half])<<1));
        #pragma unroll
        for (int oct=0;oct<4;oct++)
          acc2[mti][oct] = __builtin_amdgcn_mfma_f32_16x16x32_f16(bf[oct], a, acc2[mti][oct], 0,0,0);
      }
      __builtin_amdgcn_s_setprio(0);
      #pragma unroll
      for (int oct=0;oct<4;oct++) bf[oct] = bfn[oct];
    }
    __syncthreads();   // ALL waves done reading h1 before h2 overwrites it (h2 aliases h1)
    // h2 write (relu, LDS swizzle)
    #pragma unroll
    for (int mti=0;mti<4;mti++) if (mti < nmt){
      int m = mtid[mti]*16 + lr;
      if (m < 196){
        int py = m/14, px = m - py*14;
        int base = (py*14+px)*64; int key = (px&7)<<3;
        #pragma unroll
        for (int oct=0;oct<4;oct++){
          f16x4 wv4;
          #pragma unroll
          for (int reg=0;reg<4;reg++) wv4[reg] = (f16)fmaxf(acc2[mti][oct][reg], 0.f);
          *(f16x4*)(smem + OFF_H2 + ((base + ((oct*16 + lq*4) ^ key))<<1)) = wv4;
        }
      }
    }
  }
  __syncthreads();

  // ---- conv3: M=144(12x12, 9 tiles), N=2(pad 16), K=576; w3 from L2, next-kc prefetch ----
  {
    const int nm3 = (wv==0) ? 3 : 2;
    const int m3t[3] = {wv, 4+wv, 8};
    int rowOf[3][3], colc[3][3][2];
    #pragma unroll
    for (int i=0;i<3;i++){
      int m = m3t[i]*16 + lr;           // < 144
      int py = m/12, px = m - py*12;
      int Cy = r0 + py;
      int Cx = iclamp(c0+px, 0, W_HI-1);
      #pragma unroll
      for (int d=0;d<3;d++){
        rowOf[i][d] = (iclamp(Cy+d-1, 0, H_HI-1) - (r0-1))*896;  // *14*64
        int vv = iclamp(Cx+d-1, 0, W_HI-1) - (c0-1);
        int key = (vv&7)<<3;
        colc[i][d][0] = vv*64 + ((lq*8) ^ key);
        colc[i][d][1] = vv*64 + ((32+lq*8) ^ key);
      }
    }
    f32x4 acc3[3] = {{0,0,0,0},{0,0,0,0},{0,0,0,0}};
    const int cidx = ln&1;
    const f16* w3b = wbuf + 45056;
    f16x8 b = *(const f16x8*)(w3b + cidx*576 + lq*8);
    #pragma unroll
    for (int kc=0;kc<18;kc++){
      const int tap = kc>>1, half = kc&1;
      const int dy = tap/3, dx = tap - dy*3;
      f16x8 bn;
      if (kc < 17) bn = *(const f16x8*)(w3b + cidx*576 + (kc+1)*32 + lq*8);
      __builtin_amdgcn_s_setprio(1);
      #pragma unroll
      for (int i=0;i<3;i++) if (i < nm3){
        f16x8 a = *(const f16x8*)(smem + OFF_H2 + ((rowOf[i][dy] + colc[i][dx][half])<<1));
        acc3[i] = __builtin_amdgcn_mfma_f32_16x16x32_f16(a, b, acc3[i], 0,0,0);
      }
      __builtin_amdgcn_s_setprio(0);
      b = bn;
    }
    __syncthreads();   // conv3 reads of h2 done before res write (res aliases cnn region)
    float* sres = (float*)(smem + OFF_RES);
    if (lr < 2){
      float bv = b3g[lr];
      #pragma unroll
      for (int i=0;i<3;i++) if (i < nm3){
        #pragma unroll
        for (int reg=0;reg<4;reg++){
          int m = m3t[i]*16 + lq*4 + reg;
          sres[lr*144 + m] = acc3[i][reg] + bv;
        }
      }
    }
  }
  __syncthreads();

  // ---- blend + outputs over 12x12 ----
  if (tid < 144){
    int ty = tid/12, tx = tid - ty*12;
    int gy = r0 + ty, gx = c0 + tx;
    if (gx < W_HI){
      const float* sres = (const float*)(smem + OFF_RES);
      float a0 = sres[tid], a1 = sres[144+tid];
      float alpha = fminf(fmaxf(a0, 0.0f), 1.0f);
      int pix = gy*W_HI + gx;
      float4 fb = FB[(size_t)n*HW_HI + pix];
      float4 hv = hist4[pix];
      float h0 = hv.x*(1.0f-alpha) + fb.x*alpha;
      float h1 = hv.y*(1.0f-alpha) + fb.y*alpha;
      float h2 = hv.z*(1.0f-alpha) + fb.z*alpha;
      float h3 = hv.w*(1.0f-alpha) + fb.w*alpha + a1;
      h0 = fminf(fmaxf(h0,0.f),1.f); h1 = fminf(fmaxf(h1,0.f),1.f);
      h2 = fminf(fmaxf(h2,0.f),1.f); h3 = fminf(fmaxf(h3,0.f),1.f);
      histOut[(size_t)n*HW_HI + pix] = make_float4(h0,h1,h2,h3);
      float* rp = outp + (size_t)n*3*HW_HI + pix;
      rp[0] = h0; rp[HW_HI] = h1; rp[2*HW_HI] = h2;
    }
  }
}

extern "C" void kernel_launch(void* const* d_in, const int* in_sizes, int n_in,
                              void* d_out, int out_size, void* d_ws, size_t ws_size,
                              hipStream_t stream){
  const float* frames = (const float*)d_in[0];
  const float* depths = (const float*)d_in[1];
  const float* mvs    = (const float*)d_in[2];
  const float* jits   = (const float*)d_in[3];
  const float* w1 = (const float*)d_in[4];
  const float* b1 = (const float*)d_in[5];
  const float* w2 = (const float*)d_in[6];
  const float* b2 = (const float*)d_in[7];
  const float* w3 = (const float*)d_in[8];
  const float* b3 = (const float*)d_in[9];
  float* out = (float*)d_out;

  float4* FB4 = (float4*)d_ws;                     // [N][HW][4] f32 interleaved
  float4* HA  = FB4 + (size_t)NB*HW_HI;            // history ping
  float4* HB  = HA  + (size_t)NB*HW_HI;            // history pong
  f16*  wbuf = (f16*)(HB + (size_t)NB*HW_HI);      // 46592 f16 = 93184 B

  dim3 bs(256);
  int npix = NB*HW_HI;
  dim3 gpix((npix + 255)/256);
  dim3 gfused((W_HI + TILE-1)/TILE, (H_HI + TILE-1)/TILE, NB);

  k_wprep<<<dim3((46592+255)/256), bs, 0, stream>>>(w1, w2, w3, wbuf);

  for (int t = T_STEPS-1; t >= 0; --t){
    const float* fr = frames + (size_t)t*NB*3*HW_LO;
    const float* dp = depths + (size_t)t*NB*HW_LO;
    const float* mv = mvs    + (size_t)t*NB*HW_LO*2;
    const float* jt = jits   + (size_t)t*NB*2;
    float* ot = out + (size_t)t*NB*3*HW_HI;
    int doWarp = (t != T_STEPS-1) ? 1 : 0;

    k_pw<<<gpix, bs, 0, stream>>>(HA, mv, fr, dp, jt, FB4, HB, doWarp);
    const float4* histIn = doWarp ? (const float4*)HB : (const float4*)FB4;
    k_fused<<<gfused, bs, 0, stream>>>(fr, dp, jt, histIn, FB4, wbuf,
        b1, b2, b3, HA, ot);
  }
}

// Round 15
// 1272.438 us; speedup vs baseline: 1.0975x; 1.0975x over previous
//
#include <hip/hip_runtime.h>

#define T_STEPS 3
#define NB 2
#define H_LO 360
#define W_LO 640
#define H_HI 720
#define W_HI 1280
#define HW_LO (H_LO*W_LO)
#define HW_HI (H_HI*W_HI)
#define TILE 12

typedef _Float16 f16;
typedef __attribute__((ext_vector_type(4))) _Float16 f16x4;
typedef __attribute__((ext_vector_type(8))) _Float16 f16x8;
typedef __attribute__((ext_vector_type(4))) float f32x4;

// LDS map (total 37952 B -> 3 blocks/CU at bound-3):
//  h1 f16 [16][16][64 swz]  @0      32768 B
//  h2 f16 [14][14][64 swz]  @0      25088 B (ALIASES h1; h1 dead after conv2 MFMAs + barrier)
//  cnn_in f16 [18][18][8]   @32768   5184 B (dead after conv1)
//  res f32 [2][144]         @32768   1152 B (aliases cnn; written in conv3 epilogue)
#define OFF_H1  0
#define OFF_H2  0
#define OFF_CNN 32768
#define OFF_RES 32768
#define LDS_BYTES 37952

__device__ __forceinline__ int imin(int a,int b){return a<b?a:b;}
__device__ __forceinline__ int imax(int a,int b){return a>b?a:b;}
__device__ __forceinline__ int iclamp(int v,int lo,int hi){return imin(imax(v,lo),hi);}

__device__ __forceinline__ float depth_tx(float d0){
  float d = 10.0f / (100.0f - d0*99.9f);
  return (d - 0.1f) / 99.9f;
}

__device__ __forceinline__ void cubw(float t, float* w){
  const float a = -0.75f;
  float t2 = t*t, t3 = t2*t;
  w[0] = a*(t3 - 2.0f*t2 + t);
  w[1] = (a+2.0f)*t3 - (a+3.0f)*t2 + 1.0f;
  float s = 1.0f - t;
  w[2] = (a+2.0f)*s*s*s - (a+3.0f)*s*s + 1.0f;
  float u = 2.0f - t;
  w[3] = a*u*u*u - 5.0f*a*u*u + 8.0f*a*u - 4.0f*a;
}

// jitter-aligned bicubic upsample of [frame rgb, depth_tx] at hi-res pixel (x,y)
__device__ __forceinline__ float4 fb_bicubic(const float* __restrict__ fbase,
    const float* __restrict__ dbase, float jx, float jy, int x, int y){
  float gx = (2.0f*(float)x + 1.0f)/(float)W_HI - 1.0f + 2.0f*(0.5f - jx)/(float)W_LO;
  float gy = (2.0f*(float)y + 1.0f)/(float)H_HI - 1.0f + 2.0f*(0.5f - jy)/(float)H_LO;
  float ix = ((gx + 1.0f)*(float)W_LO - 1.0f)*0.5f;
  float iy = ((gy + 1.0f)*(float)H_LO - 1.0f)*0.5f;
  float xf = floorf(ix), yf = floorf(iy);
  float tx = ix - xf, ty = iy - yf;
  int xi = (int)xf, yi = (int)yf;
  float wx[4], wy[4]; cubw(tx, wx); cubw(ty, wy);
  int xs[4], ys[4];
  #pragma unroll
  for (int j=0;j<4;j++){ xs[j]=iclamp(xi-1+j,0,W_LO-1); ys[j]=iclamp(yi-1+j,0,H_LO-1); }
  float a0=0.f,a1=0.f,a2=0.f,a3=0.f;
  #pragma unroll
  for (int i=0;i<4;i++){
    #pragma unroll
    for (int j=0;j<4;j++){
      float wgt = wy[i]*wx[j];
      int off = ys[i]*W_LO + xs[j];
      a0 += wgt*fbase[off];
      a1 += wgt*fbase[HW_LO+off];
      a2 += wgt*fbase[2*HW_LO+off];
      a3 += wgt*depth_tx(dbase[off]);
    }
  }
  return make_float4(a0,a1,a2,a3);
}

// ---------------- weight prep (EXACT R10 layout): f32 -> f16, relayout + XOR-swizzle ----------------
// wbuf f16: [0,8192) w1 [oc64][kk128]; [8192,45056) w2 [oc64][kk576]; [45056,46208) w3 [2][576]; pad to 46592
__global__ __launch_bounds__(256) void k_wprep(const float* __restrict__ w1g,
    const float* __restrict__ w2g, const float* __restrict__ w3g, f16* __restrict__ wbuf){
  int i = blockIdx.x*256 + threadIdx.x;
  if (i >= 46592) return;
  float val = 0.0f;
  if (i < 8192){
    int oc = i>>7, kk = i&127, k = kk ^ ((oc&7)<<3);      // k = tap*8+ic, pad [72,128)=0
    if (k < 72) val = w1g[(oc*8 + (k&7))*9 + (k>>3)];
  } else if (i < 45056){
    int j = i - 8192; int oc = j/576, kk = j - oc*576, k = kk ^ ((oc&7)<<3); // k = tap*64+ic
    val = w2g[(oc*64 + (k&63))*9 + (k>>6)];
  } else {
    int j = i - 45056;
    if (j < 1152){ int nn = j/576, k = j - nn*576;
      val = w3g[(nn*64 + (k&63))*9 + (k>>6)];
    }
  }
  wbuf[i] = (f16)val;
}

// ---------------- k_pw: FB4 = bicubic prep (always); histB = mv-warp of histA, OOB -> FB (if doWarp) ----------------
__global__ __launch_bounds__(256) void k_pw(const float4* __restrict__ histA,
    const float* __restrict__ mv, const float* __restrict__ frame,
    const float* __restrict__ depth, const float* __restrict__ jit,
    float4* __restrict__ FB, float4* __restrict__ histB, int doWarp){
  int idx = blockIdx.x*256 + threadIdx.x;
  if (idx >= NB*HW_HI) return;
  int n = idx / HW_HI, p = idx - n*HW_HI;
  int y = p / W_HI, x = p - y*W_HI;
  const float* fbase = frame + (size_t)n*3*HW_LO;
  const float* dbase = depth + (size_t)n*HW_LO;
  float4 fb4 = fb_bicubic(fbase, dbase, jit[n*2], jit[n*2+1], x, y);
  FB[(size_t)n*HW_HI + p] = fb4;
  if (!doWarp) return;

  float cy = fmaxf(((float)y + 0.5f)/2.0f - 0.5f, 0.0f);
  float cx = fmaxf(((float)x + 0.5f)/2.0f - 0.5f, 0.0f);
  float y0f = floorf(cy), x0f = floorf(cx);
  float tyv = cy - y0f, txv = cx - x0f;
  int y0 = iclamp((int)y0f, 0, H_LO-1), y1 = iclamp((int)y0f+1, 0, H_LO-1);
  int x0 = iclamp((int)x0f, 0, W_LO-1), x1 = iclamp((int)x0f+1, 0, W_LO-1);
  const float* mb = mv + (size_t)n*HW_LO*2;
  float gx, gy;
  {
    float v00 = mb[(y0*W_LO+x0)*2], v01 = mb[(y0*W_LO+x1)*2];
    float v10 = mb[(y1*W_LO+x0)*2], v11 = mb[(y1*W_LO+x1)*2];
    float r0 = v00*(1.0f-tyv) + v10*tyv;
    float r1 = v01*(1.0f-tyv) + v11*tyv;
    gx = r0*(1.0f-txv) + r1*txv;
  }
  {
    float v00 = mb[(y0*W_LO+x0)*2+1], v01 = mb[(y0*W_LO+x1)*2+1];
    float v10 = mb[(y1*W_LO+x0)*2+1], v11 = mb[(y1*W_LO+x1)*2+1];
    float r0 = v00*(1.0f-tyv) + v10*tyv;
    float r1 = v01*(1.0f-tyv) + v11*tyv;
    gy = r0*(1.0f-txv) + r1*txv;
  }
  bool oob = (gx > 1.0f) || (gx < -1.0f) || (gy > 1.0f) || (gy < -1.0f);
  float4 res;
  if (oob) {
    res = fb4;   // same value as FB[n*HW+p] just computed
  } else {
    const float4* hb = histA + (size_t)n*HW_HI;
    float ix = ((gx + 1.0f)*(float)W_HI - 1.0f)*0.5f;
    float iy = ((gy + 1.0f)*(float)H_HI - 1.0f)*0.5f;
    float xf = floorf(ix), yf = floorf(iy);
    float tx = ix - xf, ty = iy - yf;
    int xi = (int)xf, yi = (int)yf;
    float wx[4], wy[4]; cubw(tx, wx); cubw(ty, wy);
    int xs[4], ys[4];
    #pragma unroll
    for (int j=0;j<4;j++){ xs[j]=iclamp(xi-1+j,0,W_HI-1); ys[j]=iclamp(yi-1+j,0,H_HI-1); }
    float a0=0.f,a1=0.f,a2=0.f,a3=0.f;
    #pragma unroll
    for (int i=0;i<4;i++){
      #pragma unroll
      for (int j=0;j<4;j++){
        float wgt = wy[i]*wx[j];
        float4 v = hb[ys[i]*W_HI + xs[j]];
        a0 += wgt*v.x; a1 += wgt*v.y; a2 += wgt*v.z; a3 += wgt*v.w;
      }
    }
    res = make_float4(a0,a1,a2,a3);
  }
  histB[(size_t)n*HW_HI + p] = res;
}

// ---------------- fused conv1+conv2+conv3 (EXACT R13: MFMA f16, swizzled weights from L2, h2-aliases-h1) ----------------
__global__ __launch_bounds__(256,3) void k_fused(
    const float* __restrict__ frame, const float* __restrict__ depth,
    const float* __restrict__ jit, const float4* __restrict__ histIn,
    const float4* __restrict__ FB, const f16* __restrict__ wbuf,
    const float* __restrict__ b1g, const float* __restrict__ b2g, const float* __restrict__ b3g,
    float4* __restrict__ histOut, float* __restrict__ outp)
{
  __shared__ __attribute__((aligned(16))) char smem[LDS_BYTES];
  const int tid = threadIdx.x;
  const int wv = tid>>6, ln = tid&63, lr = ln&15, lq = ln>>4;
  const int n  = blockIdx.z;
  const int r0 = blockIdx.y * TILE;
  const int c0 = blockIdx.x * TILE;
  const float jx = jit[n*2], jy = jit[n*2+1];
  const int jix = (int)floorf(jx*2.0f), jiy = (int)floorf(jy*2.0f);
  const float* fbase = frame + (size_t)n*3*HW_LO;
  const float* dbase = depth + (size_t)n*HW_LO;
  const float4* hist4 = histIn + (size_t)n*HW_HI;
  const int wkk = (lr&7)<<3;     // weight k-swizzle key (oc&7 == lr&7)

  // prefetch conv1 weight fragments from global (latency hides under stage A)
  f16x8 B1[3][4];
  #pragma unroll
  for (int kc=0;kc<3;kc++)
    #pragma unroll
    for (int oct=0;oct<4;oct++){
      int oc = oct*16 + lr;
      int k0 = kc*32 + lq*8;
      B1[kc][oct] = *(const f16x8*)(wbuf + oc*128 + (k0 ^ wkk));
    }

  // ---- Stage A: cnn_in tile (18x18x8) ----
  for (int e=tid; e<324; e+=256){
    int u = e/18, v = e - u*18;
    int cgy = iclamp(r0-3+u, 0, H_HI-1);
    int cgx = iclamp(c0-3+v, 0, W_HI-1);
    float v0=0.f, v1=0.f, v2=0.f, v3=0.f;
    int yy = cgy - jiy, xx = cgx - jix;
    if (yy>=0 && xx>=0 && !(yy&1) && !(xx&1)){
      int off = (yy>>1)*W_LO + (xx>>1);
      v0 = fbase[off]; v1 = fbase[HW_LO+off]; v2 = fbase[2*HW_LO+off];
      v3 = depth_tx(dbase[off]);
    }
    float4 h = hist4[cgy*W_HI + cgx];
    f16x8 pk;
    pk[0]=(f16)v0; pk[1]=(f16)v1; pk[2]=(f16)v2; pk[3]=(f16)v3;
    pk[4]=(f16)h.x; pk[5]=(f16)h.y; pk[6]=(f16)h.z; pk[7]=(f16)h.w;
    *(f16x8*)(smem + OFF_CNN + e*16) = pk;
  }
  __syncthreads();

  // ---- conv1: D[oc][px] (weights as A-operand), M=oc 64, N=16 px/row, K=96 (pad of 72) ----
  {
    float4 b1v[4];
    #pragma unroll
    for (int oct=0;oct<4;oct++) b1v[oct] = *(const float4*)(b1g + oct*16 + lq*4);
    #pragma unroll
    for (int ty4=0;ty4<4;ty4++){
      int ty = wv*4 + ty4;
      int g1y = iclamp(r0-2+ty, 0, H_HI-1);
      int g1x = iclamp(c0-2+lr, 0, W_HI-1);
      f32x4 acc[4];
      #pragma unroll
      for (int oct=0;oct<4;oct++) acc[oct] = (f32x4){b1v[oct].x,b1v[oct].y,b1v[oct].z,b1v[oct].w};
      #pragma unroll
      for (int kc=0;kc<3;kc++){
        int k0 = kc*32 + lq*8;
        int t = imin(k0>>3, 8);
        int dy = (t*11)>>5; int dx = t - dy*3;
        int uu = iclamp(g1y+dy-1, 0, H_HI-1) - (r0-3);
        int vv = iclamp(g1x+dx-1, 0, W_HI-1) - (c0-3);
        f16x8 a = *(const f16x8*)(smem + OFF_CNN + (uu*18+vv)*16);
        #pragma unroll
        for (int oct=0;oct<4;oct++)
          acc[oct] = __builtin_amdgcn_mfma_f32_16x16x32_f16(B1[kc][oct], a, acc[oct], 0,0,0);
      }
      // h1 write (LDS swizzle): pixel = (ty, lr), oc = oct*16+lq*4+reg -> one f16x4 per oct
      #pragma unroll
      for (int oct=0;oct<4;oct++){
        f16x4 wv4;
        #pragma unroll
        for (int reg=0;reg<4;reg++) wv4[reg] = (f16)fmaxf(acc[oct][reg], 0.f);
        int oc0 = (oct*16 + lq*4) ^ ((lr&7)<<3);
        *(f16x4*)(smem + OFF_H1 + (((ty*16+lr)*64 + oc0)<<1)) = wv4;
      }
    }
  }
  __syncthreads();

  // ---- conv2: D[oc][m], M=oc 64, N=196 px (13 tiles), K=576; w2 from L2, next-kc prefetch ----
  {
    const int nmt = (wv==0) ? 4 : 3;
    const int mtid[4] = {wv, 4+wv, 8+wv, 12};
    int rowOf[4][3], colc[4][3][2];
    #pragma unroll
    for (int mti=0;mti<4;mti++){
      int m = imin(mtid[mti]*16 + lr, 195);
      int py = m/14, px = m - py*14;
      int Ay = iclamp(r0-1+py, 0, H_HI-1);
      int Ax = iclamp(c0-1+px, 0, W_HI-1);
      #pragma unroll
      for (int d=0;d<3;d++){
        rowOf[mti][d] = (iclamp(Ay+d-1, 0, H_HI-1) - (r0-2))*1024;  // *16*64
        int vv = iclamp(Ax+d-1, 0, W_HI-1) - (c0-2);
        int key = (vv&7)<<3;
        colc[mti][d][0] = vv*64 + ((lq*8) ^ key);
        colc[mti][d][1] = vv*64 + ((32+lq*8) ^ key);
      }
    }
    float4 b2v[4];
    #pragma unroll
    for (int oct=0;oct<4;oct++) b2v[oct] = *(const float4*)(b2g + oct*16 + lq*4);
    f32x4 acc2[4][4];
    #pragma unroll
    for (int mti=0;mti<4;mti++)
      #pragma unroll
      for (int oct=0;oct<4;oct++) acc2[mti][oct] = (f32x4){b2v[oct].x,b2v[oct].y,b2v[oct].z,b2v[oct].w};
    const f16* w2b = wbuf + 8192;   // [oc64][k576 swz]
    // prefetch kc=0 weight fragments
    f16x8 bf[4];
    #pragma unroll
    for (int oct=0;oct<4;oct++)
      bf[oct] = *(const f16x8*)(w2b + (oct*16+lr)*576 + ((lq*8) ^ wkk));
    #pragma unroll
    for (int kc=0;kc<18;kc++){
      const int tap = kc>>1, half = kc&1;
      const int dy = tap/3, dx = tap - dy*3;
      f16x8 bfn[4];
      if (kc < 17){
        const int kn = kc+1, tapn = kn>>1, halfn = kn&1;
        #pragma unroll
        for (int oct=0;oct<4;oct++)
          bfn[oct] = *(const f16x8*)(w2b + (oct*16+lr)*576 + ((tapn*64 + halfn*32 + lq*8) ^ wkk));
      }
      #pragma unroll
      for (int mti=0;mti<4;mti++) if (mti < nmt){
        f16x8 a = *(const f16x8*)(smem + OFF_H1 + ((rowOf[mti][dy] + colc[mti][dx][half])<<1));
        #pragma unroll
        for (int oct=0;oct<4;oct++)
          acc2[mti][oct] = __builtin_amdgcn_mfma_f32_16x16x32_f16(bf[oct], a, acc2[mti][oct], 0,0,0);
      }
      #pragma unroll
      for (int oct=0;oct<4;oct++) bf[oct] = bfn[oct];
    }
    __syncthreads();   // ALL waves done reading h1 before h2 overwrites it (h2 aliases h1)
    // h2 write (relu, LDS swizzle)
    #pragma unroll
    for (int mti=0;mti<4;mti++) if (mti < nmt){
      int m = mtid[mti]*16 + lr;
      if (m < 196){
        int py = m/14, px = m - py*14;
        int base = (py*14+px)*64; int key = (px&7)<<3;
        #pragma unroll
        for (int oct=0;oct<4;oct++){
          f16x4 wv4;
          #pragma unroll
          for (int reg=0;reg<4;reg++) wv4[reg] = (f16)fmaxf(acc2[mti][oct][reg], 0.f);
          *(f16x4*)(smem + OFF_H2 + ((base + ((oct*16 + lq*4) ^ key))<<1)) = wv4;
        }
      }
    }
  }
  __syncthreads();

  // ---- conv3: M=144(12x12, 9 tiles), N=2(pad 16), K=576; w3 from L2, next-kc prefetch ----
  {
    const int nm3 = (wv==0) ? 3 : 2;
    const int m3t[3] = {wv, 4+wv, 8};
    int rowOf[3][3], colc[3][3][2];
    #pragma unroll
    for (int i=0;i<3;i++){
      int m = m3t[i]*16 + lr;           // < 144
      int py = m/12, px = m - py*12;
      int Cy = r0 + py;
      int Cx = iclamp(c0+px, 0, W_HI-1);
      #pragma unroll
      for (int d=0;d<3;d++){
        rowOf[i][d] = (iclamp(Cy+d-1, 0, H_HI-1) - (r0-1))*896;  // *14*64
        int vv = iclamp(Cx+d-1, 0, W_HI-1) - (c0-1);
        int key = (vv&7)<<3;
        colc[i][d][0] = vv*64 + ((lq*8) ^ key);
        colc[i][d][1] = vv*64 + ((32+lq*8) ^ key);
      }
    }
    f32x4 acc3[3] = {{0,0,0,0},{0,0,0,0},{0,0,0,0}};
    const int cidx = ln&1;
    const f16* w3b = wbuf + 45056;
    f16x8 b = *(const f16x8*)(w3b + cidx*576 + lq*8);
    #pragma unroll
    for (int kc=0;kc<18;kc++){
      const int tap = kc>>1, half = kc&1;
      const int dy = tap/3, dx = tap - dy*3;
      f16x8 bn;
      if (kc < 17) bn = *(const f16x8*)(w3b + cidx*576 + (kc+1)*32 + lq*8);
      #pragma unroll
      for (int i=0;i<3;i++) if (i < nm3){
        f16x8 a = *(const f16x8*)(smem + OFF_H2 + ((rowOf[i][dy] + colc[i][dx][half])<<1));
        acc3[i] = __builtin_amdgcn_mfma_f32_16x16x32_f16(a, b, acc3[i], 0,0,0);
      }
      b = bn;
    }
    __syncthreads();   // conv3 reads of h2 done before res write (res aliases cnn region)
    float* sres = (float*)(smem + OFF_RES);
    if (lr < 2){
      float bv = b3g[lr];
      #pragma unroll
      for (int i=0;i<3;i++) if (i < nm3){
        #pragma unroll
        for (int reg=0;reg<4;reg++){
          int m = m3t[i]*16 + lq*4 + reg;
          sres[lr*144 + m] = acc3[i][reg] + bv;
        }
      }
    }
  }
  __syncthreads();

  // ---- blend + outputs over 12x12 ----
  if (tid < 144){
    int ty = tid/12, tx = tid - ty*12;
    int gy = r0 + ty, gx = c0 + tx;
    if (gx < W_HI){
      const float* sres = (const float*)(smem + OFF_RES);
      float a0 = sres[tid], a1 = sres[144+tid];
      float alpha = fminf(fmaxf(a0, 0.0f), 1.0f);
      int pix = gy*W_HI + gx;
      float4 fb = FB[(size_t)n*HW_HI + pix];
      float4 hv = hist4[pix];
      float h0 = hv.x*(1.0f-alpha) + fb.x*alpha;
      float h1 = hv.y*(1.0f-alpha) + fb.y*alpha;
      float h2 = hv.z*(1.0f-alpha) + fb.z*alpha;
      float h3 = hv.w*(1.0f-alpha) + fb.w*alpha + a1;
      h0 = fminf(fmaxf(h0,0.f),1.f); h1 = fminf(fmaxf(h1,0.f),1.f);
      h2 = fminf(fmaxf(h2,0.f),1.f); h3 = fminf(fmaxf(h3,0.f),1.f);
      histOut[(size_t)n*HW_HI + pix] = make_float4(h0,h1,h2,h3);
      float* rp = outp + (size_t)n*3*HW_HI + pix;
      rp[0] = h0; rp[HW_HI] = h1; rp[2*HW_HI] = h2;
    }
  }
}

extern "C" void kernel_launch(void* const* d_in, const int* in_sizes, int n_in,
                              void* d_out, int out_size, void* d_ws, size_t ws_size,
                              hipStream_t stream){
  const float* frames = (const float*)d_in[0];
  const float* depths = (const float*)d_in[1];
  const float* mvs    = (const float*)d_in[2];
  const float* jits   = (const float*)d_in[3];
  const float* w1 = (const float*)d_in[4];
  const float* b1 = (const float*)d_in[5];
  const float* w2 = (const float*)d_in[6];
  const float* b2 = (const float*)d_in[7];
  const float* w3 = (const float*)d_in[8];
  const float* b3 = (const float*)d_in[9];
  float* out = (float*)d_out;

  float4* FB4 = (float4*)d_ws;                     // [N][HW][4] f32 interleaved
  float4* HA  = FB4 + (size_t)NB*HW_HI;            // history ping
  float4* HB  = HA  + (size_t)NB*HW_HI;            // history pong
  f16*  wbuf = (f16*)(HB + (size_t)NB*HW_HI);      // 46592 f16 = 93184 B

  dim3 bs(256);
  int npix = NB*HW_HI;
  dim3 gpix((npix + 255)/256);
  dim3 gfused((W_HI + TILE-1)/TILE, (H_HI + TILE-1)/TILE, NB);

  k_wprep<<<dim3((46592+255)/256), bs, 0, stream>>>(w1, w2, w3, wbuf);

  for (int t = T_STEPS-1; t >= 0; --t){
    const float* fr = frames + (size_t)t*NB*3*HW_LO;
    const float* dp = depths + (size_t)t*NB*HW_LO;
    const float* mv = mvs    + (size_t)t*NB*HW_LO*2;
    const float* jt = jits   + (size_t)t*NB*2;
    float* ot = out + (size_t)t*NB*3*HW_HI;
    int doWarp = (t != T_STEPS-1) ? 1 : 0;

    k_pw<<<gpix, bs, 0, stream>>>(HA, mv, fr, dp, jt, FB4, HB, doWarp);
    const float4* histIn = doWarp ? (const float4*)HB : (const float4*)FB4;
    k_fused<<<gfused, bs, 0, stream>>>(fr, dp, jt, histIn, FB4, wbuf,
        b1, b2, b3, HA, ot);
  }
}

// Round 16
// 1126.348 us; speedup vs baseline: 1.2399x; 1.1297x over previous
//
#include <hip/hip_runtime.h>

#define T_STEPS 3
#define NB 2
#define H_LO 360
#define W_LO 640
#define H_HI 720
#define W_HI 1280
#define HW_LO (H_LO*W_LO)
#define HW_HI (H_HI*W_HI)
#define TILE 14

typedef _Float16 f16;
typedef __attribute__((ext_vector_type(4))) _Float16 f16x4;
typedef __attribute__((ext_vector_type(8))) _Float16 f16x8;
typedef __attribute__((ext_vector_type(4))) float f32x4;

// LDS map (total 47872 B -> 3 blocks/CU at bound-3), TILE=14:
//  h1 f16 [18*18 px][64 swz]  @0      41472 B
//  h2 f16 [16*16 px][64 swz]  @0      32768 B (ALIASES h1; h1 dead after conv2 MFMAs + barrier)
//  cnn_in f16 [20*20 px][8]   @41472   6400 B (dead after conv1)
//  res f32 [2][196]           @41472   1568 B (aliases cnn; written in conv3 epilogue)
#define OFF_H1  0
#define OFF_H2  0
#define OFF_CNN 41472
#define OFF_RES 41472
#define LDS_BYTES 47872

__device__ __forceinline__ int imin(int a,int b){return a<b?a:b;}
__device__ __forceinline__ int imax(int a,int b){return a>b?a:b;}
__device__ __forceinline__ int iclamp(int v,int lo,int hi){return imin(imax(v,lo),hi);}

__device__ __forceinline__ float depth_tx(float d0){
  float d = 10.0f / (100.0f - d0*99.9f);
  return (d - 0.1f) / 99.9f;
}

__device__ __forceinline__ void cubw(float t, float* w){
  const float a = -0.75f;
  float t2 = t*t, t3 = t2*t;
  w[0] = a*(t3 - 2.0f*t2 + t);
  w[1] = (a+2.0f)*t3 - (a+3.0f)*t2 + 1.0f;
  float s = 1.0f - t;
  w[2] = (a+2.0f)*s*s*s - (a+3.0f)*s*s + 1.0f;
  float u = 2.0f - t;
  w[3] = a*u*u*u - 5.0f*a*u*u + 8.0f*a*u - 4.0f*a;
}

// jitter-aligned bicubic upsample of [frame rgb, depth_tx] at hi-res pixel (x,y)
__device__ __forceinline__ float4 fb_bicubic(const float* __restrict__ fbase,
    const float* __restrict__ dbase, float jx, float jy, int x, int y){
  float gx = (2.0f*(float)x + 1.0f)/(float)W_HI - 1.0f + 2.0f*(0.5f - jx)/(float)W_LO;
  float gy = (2.0f*(float)y + 1.0f)/(float)H_HI - 1.0f + 2.0f*(0.5f - jy)/(float)H_LO;
  float ix = ((gx + 1.0f)*(float)W_LO - 1.0f)*0.5f;
  float iy = ((gy + 1.0f)*(float)H_LO - 1.0f)*0.5f;
  float xf = floorf(ix), yf = floorf(iy);
  float tx = ix - xf, ty = iy - yf;
  int xi = (int)xf, yi = (int)yf;
  float wx[4], wy[4]; cubw(tx, wx); cubw(ty, wy);
  int xs[4], ys[4];
  #pragma unroll
  for (int j=0;j<4;j++){ xs[j]=iclamp(xi-1+j,0,W_LO-1); ys[j]=iclamp(yi-1+j,0,H_LO-1); }
  float a0=0.f,a1=0.f,a2=0.f,a3=0.f;
  #pragma unroll
  for (int i=0;i<4;i++){
    #pragma unroll
    for (int j=0;j<4;j++){
      float wgt = wy[i]*wx[j];
      int off = ys[i]*W_LO + xs[j];
      a0 += wgt*fbase[off];
      a1 += wgt*fbase[HW_LO+off];
      a2 += wgt*fbase[2*HW_LO+off];
      a3 += wgt*depth_tx(dbase[off]);
    }
  }
  return make_float4(a0,a1,a2,a3);
}

// ---------------- weight prep (EXACT R10 layout): f32 -> f16, relayout + XOR-swizzle ----------------
// wbuf f16: [0,8192) w1 [oc64][kk128]; [8192,45056) w2 [oc64][kk576]; [45056,46208) w3 [2][576]; pad to 46592
__global__ __launch_bounds__(256) void k_wprep(const float* __restrict__ w1g,
    const float* __restrict__ w2g, const float* __restrict__ w3g, f16* __restrict__ wbuf){
  int i = blockIdx.x*256 + threadIdx.x;
  if (i >= 46592) return;
  float val = 0.0f;
  if (i < 8192){
    int oc = i>>7, kk = i&127, k = kk ^ ((oc&7)<<3);      // k = tap*8+ic, pad [72,128)=0
    if (k < 72) val = w1g[(oc*8 + (k&7))*9 + (k>>3)];
  } else if (i < 45056){
    int j = i - 8192; int oc = j/576, kk = j - oc*576, k = kk ^ ((oc&7)<<3); // k = tap*64+ic
    val = w2g[(oc*64 + (k&63))*9 + (k>>6)];
  } else {
    int j = i - 45056;
    if (j < 1152){ int nn = j/576, k = j - nn*576;
      val = w3g[(nn*64 + (k&63))*9 + (k>>6)];
    }
  }
  wbuf[i] = (f16)val;
}

// ---------------- k_pw: FB4 = bicubic prep (always); histB = mv-warp of histA, OOB -> FB (if doWarp) ----------------
__global__ __launch_bounds__(256) void k_pw(const float4* __restrict__ histA,
    const float* __restrict__ mv, const float* __restrict__ frame,
    const float* __restrict__ depth, const float* __restrict__ jit,
    float4* __restrict__ FB, float4* __restrict__ histB, int doWarp){
  int idx = blockIdx.x*256 + threadIdx.x;
  if (idx >= NB*HW_HI) return;
  int n = idx / HW_HI, p = idx - n*HW_HI;
  int y = p / W_HI, x = p - y*W_HI;
  const float* fbase = frame + (size_t)n*3*HW_LO;
  const float* dbase = depth + (size_t)n*HW_LO;
  float4 fb4 = fb_bicubic(fbase, dbase, jit[n*2], jit[n*2+1], x, y);
  FB[(size_t)n*HW_HI + p] = fb4;
  if (!doWarp) return;

  float cy = fmaxf(((float)y + 0.5f)/2.0f - 0.5f, 0.0f);
  float cx = fmaxf(((float)x + 0.5f)/2.0f - 0.5f, 0.0f);
  float y0f = floorf(cy), x0f = floorf(cx);
  float tyv = cy - y0f, txv = cx - x0f;
  int y0 = iclamp((int)y0f, 0, H_LO-1), y1 = iclamp((int)y0f+1, 0, H_LO-1);
  int x0 = iclamp((int)x0f, 0, W_LO-1), x1 = iclamp((int)x0f+1, 0, W_LO-1);
  const float* mb = mv + (size_t)n*HW_LO*2;
  float gx, gy;
  {
    float v00 = mb[(y0*W_LO+x0)*2], v01 = mb[(y0*W_LO+x1)*2];
    float v10 = mb[(y1*W_LO+x0)*2], v11 = mb[(y1*W_LO+x1)*2];
    float r0 = v00*(1.0f-tyv) + v10*tyv;
    float r1 = v01*(1.0f-tyv) + v11*tyv;
    gx = r0*(1.0f-txv) + r1*txv;
  }
  {
    float v00 = mb[(y0*W_LO+x0)*2+1], v01 = mb[(y0*W_LO+x1)*2+1];
    float v10 = mb[(y1*W_LO+x0)*2+1], v11 = mb[(y1*W_LO+x1)*2+1];
    float r0 = v00*(1.0f-tyv) + v10*tyv;
    float r1 = v01*(1.0f-tyv) + v11*tyv;
    gy = r0*(1.0f-txv) + r1*txv;
  }
  bool oob = (gx > 1.0f) || (gx < -1.0f) || (gy > 1.0f) || (gy < -1.0f);
  float4 res;
  if (oob) {
    res = fb4;   // same value as FB[n*HW+p] just computed
  } else {
    const float4* hb = histA + (size_t)n*HW_HI;
    float ix = ((gx + 1.0f)*(float)W_HI - 1.0f)*0.5f;
    float iy = ((gy + 1.0f)*(float)H_HI - 1.0f)*0.5f;
    float xf = floorf(ix), yf = floorf(iy);
    float tx = ix - xf, ty = iy - yf;
    int xi = (int)xf, yi = (int)yf;
    float wx[4], wy[4]; cubw(tx, wx); cubw(ty, wy);
    int xs[4], ys[4];
    #pragma unroll
    for (int j=0;j<4;j++){ xs[j]=iclamp(xi-1+j,0,W_HI-1); ys[j]=iclamp(yi-1+j,0,H_HI-1); }
    float a0=0.f,a1=0.f,a2=0.f,a3=0.f;
    #pragma unroll
    for (int i=0;i<4;i++){
      #pragma unroll
      for (int j=0;j<4;j++){
        float wgt = wy[i]*wx[j];
        float4 v = hb[ys[i]*W_HI + xs[j]];
        a0 += wgt*v.x; a1 += wgt*v.y; a2 += wgt*v.z; a3 += wgt*v.w;
      }
    }
    res = make_float4(a0,a1,a2,a3);
  }
  histB[(size_t)n*HW_HI + p] = res;
}

// ---------------- fused conv1+conv2+conv3 (R13 schedule, TILE=14 geometry) ----------------
__global__ __launch_bounds__(256,3) void k_fused(
    const float* __restrict__ frame, const float* __restrict__ depth,
    const float* __restrict__ jit, const float4* __restrict__ histIn,
    const float4* __restrict__ FB, const f16* __restrict__ wbuf,
    const float* __restrict__ b1g, const float* __restrict__ b2g, const float* __restrict__ b3g,
    float4* __restrict__ histOut, float* __restrict__ outp)
{
  __shared__ __attribute__((aligned(16))) char smem[LDS_BYTES];
  const int tid = threadIdx.x;
  const int wv = tid>>6, ln = tid&63, lr = ln&15, lq = ln>>4;
  const int n  = blockIdx.z;
  const int r0 = blockIdx.y * TILE;
  const int c0 = blockIdx.x * TILE;
  const float jx = jit[n*2], jy = jit[n*2+1];
  const int jix = (int)floorf(jx*2.0f), jiy = (int)floorf(jy*2.0f);
  const float* fbase = frame + (size_t)n*3*HW_LO;
  const float* dbase = depth + (size_t)n*HW_LO;
  const float4* hist4 = histIn + (size_t)n*HW_HI;
  const int wkk = (lr&7)<<3;     // weight k-swizzle key (oc&7 == lr&7)

  // prefetch conv1 weight fragments from global (latency hides under stage A)
  f16x8 B1[3][4];
  #pragma unroll
  for (int kc=0;kc<3;kc++)
    #pragma unroll
    for (int oct=0;oct<4;oct++){
      int oc = oct*16 + lr;
      int k0 = kc*32 + lq*8;
      B1[kc][oct] = *(const f16x8*)(wbuf + oc*128 + (k0 ^ wkk));
    }

  // ---- Stage A: cnn_in tile (20x20 px, 8ch) ----
  for (int e=tid; e<400; e+=256){
    int u = e/20, v = e - u*20;
    int cgy = iclamp(r0-3+u, 0, H_HI-1);
    int cgx = iclamp(c0-3+v, 0, W_HI-1);
    float v0=0.f, v1=0.f, v2=0.f, v3=0.f;
    int yy = cgy - jiy, xx = cgx - jix;
    if (yy>=0 && xx>=0 && !(yy&1) && !(xx&1)){
      int off = (yy>>1)*W_LO + (xx>>1);
      v0 = fbase[off]; v1 = fbase[HW_LO+off]; v2 = fbase[2*HW_LO+off];
      v3 = depth_tx(dbase[off]);
    }
    float4 h = hist4[cgy*W_HI + cgx];
    f16x8 pk;
    pk[0]=(f16)v0; pk[1]=(f16)v1; pk[2]=(f16)v2; pk[3]=(f16)v3;
    pk[4]=(f16)h.x; pk[5]=(f16)h.y; pk[6]=(f16)h.z; pk[7]=(f16)h.w;
    *(f16x8*)(smem + OFF_CNN + e*16) = pk;
  }
  __syncthreads();

  // ---- conv1: D[oc][m] over h1 grid 18x18 = 324 px (21 m-tiles: 6,5,5,5), K=96 (pad of 72) ----
  {
    float4 b1v[4];
    #pragma unroll
    for (int oct=0;oct<4;oct++) b1v[oct] = *(const float4*)(b1g + oct*16 + lq*4);
    const int nmt1 = (wv==0) ? 6 : 5;
    #pragma unroll
    for (int i=0;i<6;i++) if (i < nmt1){
      int tile = (i<5) ? (4*i + wv) : 20;
      int m = tile*16 + lr;
      int mc = imin(m, 323);
      int py = mc/18, px = mc - 18*py;
      int Ay = iclamp(r0-2+py, 0, H_HI-1);
      int Ax = iclamp(c0-2+px, 0, W_HI-1);
      f32x4 acc[4];
      #pragma unroll
      for (int oct=0;oct<4;oct++) acc[oct] = (f32x4){b1v[oct].x,b1v[oct].y,b1v[oct].z,b1v[oct].w};
      #pragma unroll
      for (int kc=0;kc<3;kc++){
        int k0 = kc*32 + lq*8;
        int t = imin(k0>>3, 8);
        int dy = (t*11)>>5; int dx = t - dy*3;
        int uu = iclamp(Ay+dy-1, 0, H_HI-1) - (r0-3);
        int vv = iclamp(Ax+dx-1, 0, W_HI-1) - (c0-3);
        f16x8 a = *(const f16x8*)(smem + OFF_CNN + (uu*20+vv)*16);
        #pragma unroll
        for (int oct=0;oct<4;oct++)
          acc[oct] = __builtin_amdgcn_mfma_f32_16x16x32_f16(B1[kc][oct], a, acc[oct], 0,0,0);
      }
      // h1 write (LDS swizzle): lane's pixel = m (D col = lr), oc = oct*16+lq*4+reg
      if (m < 324){
        #pragma unroll
        for (int oct=0;oct<4;oct++){
          f16x4 wv4;
          #pragma unroll
          for (int reg=0;reg<4;reg++) wv4[reg] = (f16)fmaxf(acc[oct][reg], 0.f);
          int oc0 = (oct*16 + lq*4) ^ ((px&7)<<3);
          *(f16x4*)(smem + OFF_H1 + ((m*64 + oc0)<<1)) = wv4;
        }
      }
    }
  }
  __syncthreads();

  // ---- conv2: D[oc][m] over h2 grid 16x16 = 256 px (16 m-tiles, 4/wave, balanced), K=576 ----
  {
    const int mt0 = wv;  // tiles wv, 4+wv, 8+wv, 12+wv
    int rowOf[4][3], colc[4][3][2];
    #pragma unroll
    for (int mti=0;mti<4;mti++){
      int m = (mt0 + 4*mti)*16 + lr;       // < 256 always
      int py = m>>4, px = m&15;
      int Ay = iclamp(r0-1+py, 0, H_HI-1);
      int Ax = iclamp(c0-1+px, 0, W_HI-1);
      #pragma unroll
      for (int d=0;d<3;d++){
        rowOf[mti][d] = (iclamp(Ay+d-1, 0, H_HI-1) - (r0-2))*1152;  // *18*64
        int vv = iclamp(Ax+d-1, 0, W_HI-1) - (c0-2);
        int key = (vv&7)<<3;
        colc[mti][d][0] = vv*64 + ((lq*8) ^ key);
        colc[mti][d][1] = vv*64 + ((32+lq*8) ^ key);
      }
    }
    float4 b2v[4];
    #pragma unroll
    for (int oct=0;oct<4;oct++) b2v[oct] = *(const float4*)(b2g + oct*16 + lq*4);
    f32x4 acc2[4][4];
    #pragma unroll
    for (int mti=0;mti<4;mti++)
      #pragma unroll
      for (int oct=0;oct<4;oct++) acc2[mti][oct] = (f32x4){b2v[oct].x,b2v[oct].y,b2v[oct].z,b2v[oct].w};
    const f16* w2b = wbuf + 8192;   // [oc64][k576 swz]
    // prefetch kc=0 weight fragments
    f16x8 bf[4];
    #pragma unroll
    for (int oct=0;oct<4;oct++)
      bf[oct] = *(const f16x8*)(w2b + (oct*16+lr)*576 + ((lq*8) ^ wkk));
    #pragma unroll
    for (int kc=0;kc<18;kc++){
      const int tap = kc>>1, half = kc&1;
      const int dy = tap/3, dx = tap - dy*3;
      f16x8 bfn[4];
      if (kc < 17){
        const int kn = kc+1, tapn = kn>>1, halfn = kn&1;
        #pragma unroll
        for (int oct=0;oct<4;oct++)
          bfn[oct] = *(const f16x8*)(w2b + (oct*16+lr)*576 + ((tapn*64 + halfn*32 + lq*8) ^ wkk));
      }
      #pragma unroll
      for (int mti=0;mti<4;mti++){
        f16x8 a = *(const f16x8*)(smem + OFF_H1 + ((rowOf[mti][dy] + colc[mti][dx][half])<<1));
        #pragma unroll
        for (int oct=0;oct<4;oct++)
          acc2[mti][oct] = __builtin_amdgcn_mfma_f32_16x16x32_f16(bf[oct], a, acc2[mti][oct], 0,0,0);
      }
      #pragma unroll
      for (int oct=0;oct<4;oct++) bf[oct] = bfn[oct];
    }
    __syncthreads();   // ALL waves done reading h1 before h2 overwrites it (h2 aliases h1)
    // h2 write (relu, LDS swizzle): m < 256 always, no guard
    #pragma unroll
    for (int mti=0;mti<4;mti++){
      int m = (mt0 + 4*mti)*16 + lr;
      int px = m&15;
      int base = m*64; int key = (px&7)<<3;
      #pragma unroll
      for (int oct=0;oct<4;oct++){
        f16x4 wv4;
        #pragma unroll
        for (int reg=0;reg<4;reg++) wv4[reg] = (f16)fmaxf(acc2[mti][oct][reg], 0.f);
        *(f16x4*)(smem + OFF_H2 + ((base + ((oct*16 + lq*4) ^ key))<<1)) = wv4;
      }
    }
  }
  __syncthreads();

  // ---- conv3: M=196 (14x14, 13 m-tiles: 4,3,3,3), N=2(pad 16), K=576 ----
  {
    const int nm3 = (wv==0) ? 4 : 3;
    const int m3t[4] = {wv, 4+wv, 8+wv, 12};
    int rowOf[4][3], colc[4][3][2];
    #pragma unroll
    for (int i=0;i<4;i++){
      int m = imin(m3t[i]*16 + lr, 195);
      int py = m/14, px = m - 14*py;
      int Cy = iclamp(r0+py, 0, H_HI-1);
      int Cx = iclamp(c0+px, 0, W_HI-1);
      #pragma unroll
      for (int d=0;d<3;d++){
        rowOf[i][d] = (iclamp(Cy+d-1, 0, H_HI-1) - (r0-1))*1024;  // *16*64
        int vv = iclamp(Cx+d-1, 0, W_HI-1) - (c0-1);
        int key = (vv&7)<<3;
        colc[i][d][0] = vv*64 + ((lq*8) ^ key);
        colc[i][d][1] = vv*64 + ((32+lq*8) ^ key);
      }
    }
    f32x4 acc3[4] = {{0,0,0,0},{0,0,0,0},{0,0,0,0},{0,0,0,0}};
    const int cidx = ln&1;
    const f16* w3b = wbuf + 45056;
    f16x8 b = *(const f16x8*)(w3b + cidx*576 + lq*8);
    #pragma unroll
    for (int kc=0;kc<18;kc++){
      const int tap = kc>>1, half = kc&1;
      const int dy = tap/3, dx = tap - dy*3;
      f16x8 bn;
      if (kc < 17) bn = *(const f16x8*)(w3b + cidx*576 + (kc+1)*32 + lq*8);
      #pragma unroll
      for (int i=0;i<4;i++) if (i < nm3){
        f16x8 a = *(const f16x8*)(smem + OFF_H2 + ((rowOf[i][dy] + colc[i][dx][half])<<1));
        acc3[i] = __builtin_amdgcn_mfma_f32_16x16x32_f16(a, b, acc3[i], 0,0,0);
      }
      b = bn;
    }
    __syncthreads();   // conv3 reads of h2 done before res write (res aliases cnn region)
    float* sres = (float*)(smem + OFF_RES);
    if (lr < 2){
      float bv = b3g[lr];
      #pragma unroll
      for (int i=0;i<4;i++) if (i < nm3){
        #pragma unroll
        for (int reg=0;reg<4;reg++){
          int m = m3t[i]*16 + lq*4 + reg;
          if (m < 196) sres[lr*196 + m] = acc3[i][reg] + bv;
        }
      }
    }
  }
  __syncthreads();

  // ---- blend + outputs over 14x14 ----
  if (tid < 196){
    int ty = tid/14, tx = tid - 14*ty;
    int gy = r0 + ty, gx = c0 + tx;
    if (gy < H_HI && gx < W_HI){
      const float* sres = (const float*)(smem + OFF_RES);
      float a0 = sres[tid], a1 = sres[196+tid];
      float alpha = fminf(fmaxf(a0, 0.0f), 1.0f);
      int pix = gy*W_HI + gx;
      float4 fb = FB[(size_t)n*HW_HI + pix];
      float4 hv = hist4[pix];
      float h0 = hv.x*(1.0f-alpha) + fb.x*alpha;
      float h1 = hv.y*(1.0f-alpha) + fb.y*alpha;
      float h2 = hv.z*(1.0f-alpha) + fb.z*alpha;
      float h3 = hv.w*(1.0f-alpha) + fb.w*alpha + a1;
      h0 = fminf(fmaxf(h0,0.f),1.f); h1 = fminf(fmaxf(h1,0.f),1.f);
      h2 = fminf(fmaxf(h2,0.f),1.f); h3 = fminf(fmaxf(h3,0.f),1.f);
      histOut[(size_t)n*HW_HI + pix] = make_float4(h0,h1,h2,h3);
      float* rp = outp + (size_t)n*3*HW_HI + pix;
      rp[0] = h0; rp[HW_HI] = h1; rp[2*HW_HI] = h2;
    }
  }
}

extern "C" void kernel_launch(void* const* d_in, const int* in_sizes, int n_in,
                              void* d_out, int out_size, void* d_ws, size_t ws_size,
                              hipStream_t stream){
  const float* frames = (const float*)d_in[0];
  const float* depths = (const float*)d_in[1];
  const float* mvs    = (const float*)d_in[2];
  const float* jits   = (const float*)d_in[3];
  const float* w1 = (const float*)d_in[4];
  const float* b1 = (const float*)d_in[5];
  const float* w2 = (const float*)d_in[6];
  const float* b2 = (const float*)d_in[7];
  const float* w3 = (const float*)d_in[8];
  const float* b3 = (const float*)d_in[9];
  float* out = (float*)d_out;

  float4* FB4 = (float4*)d_ws;                     // [N][HW][4] f32 interleaved
  float4* HA  = FB4 + (size_t)NB*HW_HI;            // history ping
  float4* HB  = HA  + (size_t)NB*HW_HI;            // history pong
  f16*  wbuf = (f16*)(HB + (size_t)NB*HW_HI);      // 46592 f16 = 93184 B

  dim3 bs(256);
  int npix = NB*HW_HI;
  dim3 gpix((npix + 255)/256);
  dim3 gfused((W_HI + TILE-1)/TILE, (H_HI + TILE-1)/TILE, NB);

  k_wprep<<<dim3((46592+255)/256), bs, 0, stream>>>(w1, w2, w3, wbuf);

  for (int t = T_STEPS-1; t >= 0; --t){
    const float* fr = frames + (size_t)t*NB*3*HW_LO;
    const float* dp = depths + (size_t)t*NB*HW_LO;
    const float* mv = mvs    + (size_t)t*NB*HW_LO*2;
    const float* jt = jits   + (size_t)t*NB*2;
    float* ot = out + (size_t)t*NB*3*HW_HI;
    int doWarp = (t != T_STEPS-1) ? 1 : 0;

    k_pw<<<gpix, bs, 0, stream>>>(HA, mv, fr, dp, jt, FB4, HB, doWarp);
    const float4* histIn = doWarp ? (const float4*)HB : (const float4*)FB4;
    k_fused<<<gfused, bs, 0, stream>>>(fr, dp, jt, histIn, FB4, wbuf,
        b1, b2, b3, HA, ot);
  }
}

// Round 17
// 1122.284 us; speedup vs baseline: 1.2443x; 1.0036x over previous
//
#include <hip/hip_runtime.h>

#define T_STEPS 3
#define NB 2
#define H_LO 360
#define W_LO 640
#define H_HI 720
#define W_HI 1280
#define HW_LO (H_LO*W_LO)
#define HW_HI (H_HI*W_HI)
#define TILE 14

typedef _Float16 f16;
typedef __attribute__((ext_vector_type(4))) _Float16 f16x4;
typedef __attribute__((ext_vector_type(8))) _Float16 f16x8;
typedef __attribute__((ext_vector_type(4))) float f32x4;

// LDS map (total 47872 B -> 3 blocks/CU at bound-3), TILE=14:
//  h1 f16 [18*18 px][64 swz]  @0      41472 B
//  h2 f16 [16*16 px][64 swz]  @0      32768 B (ALIASES h1; h1 dead after conv2 MFMAs + barrier)
//  cnn_in f16 [20*20 px][8]   @41472   6400 B (dead after conv1)
//  res f32 [2][196]           @41472   1568 B (aliases cnn only; no h2 overlap)
#define OFF_H1  0
#define OFF_H2  0
#define OFF_CNN 41472
#define OFF_RES 41472
#define LDS_BYTES 47872

__device__ __forceinline__ int imin(int a,int b){return a<b?a:b;}
__device__ __forceinline__ int imax(int a,int b){return a>b?a:b;}
__device__ __forceinline__ int iclamp(int v,int lo,int hi){return imin(imax(v,lo),hi);}

__device__ __forceinline__ float depth_tx(float d0){
  float d = 10.0f / (100.0f - d0*99.9f);
  return (d - 0.1f) / 99.9f;
}

__device__ __forceinline__ void cubw(float t, float* w){
  const float a = -0.75f;
  float t2 = t*t, t3 = t2*t;
  w[0] = a*(t3 - 2.0f*t2 + t);
  w[1] = (a+2.0f)*t3 - (a+3.0f)*t2 + 1.0f;
  float s = 1.0f - t;
  w[2] = (a+2.0f)*s*s*s - (a+3.0f)*s*s + 1.0f;
  float u = 2.0f - t;
  w[3] = a*u*u*u - 5.0f*a*u*u + 8.0f*a*u - 4.0f*a;
}

// jitter-aligned bicubic upsample of [frame rgb, depth_tx] at hi-res pixel (x,y)
__device__ __forceinline__ float4 fb_bicubic(const float* __restrict__ fbase,
    const float* __restrict__ dbase, float jx, float jy, int x, int y){
  float gx = (2.0f*(float)x + 1.0f)/(float)W_HI - 1.0f + 2.0f*(0.5f - jx)/(float)W_LO;
  float gy = (2.0f*(float)y + 1.0f)/(float)H_HI - 1.0f + 2.0f*(0.5f - jy)/(float)H_LO;
  float ix = ((gx + 1.0f)*(float)W_LO - 1.0f)*0.5f;
  float iy = ((gy + 1.0f)*(float)H_LO - 1.0f)*0.5f;
  float xf = floorf(ix), yf = floorf(iy);
  float tx = ix - xf, ty = iy - yf;
  int xi = (int)xf, yi = (int)yf;
  float wx[4], wy[4]; cubw(tx, wx); cubw(ty, wy);
  int xs[4], ys[4];
  #pragma unroll
  for (int j=0;j<4;j++){ xs[j]=iclamp(xi-1+j,0,W_LO-1); ys[j]=iclamp(yi-1+j,0,H_LO-1); }
  float a0=0.f,a1=0.f,a2=0.f,a3=0.f;
  #pragma unroll
  for (int i=0;i<4;i++){
    #pragma unroll
    for (int j=0;j<4;j++){
      float wgt = wy[i]*wx[j];
      int off = ys[i]*W_LO + xs[j];
      a0 += wgt*fbase[off];
      a1 += wgt*fbase[HW_LO+off];
      a2 += wgt*fbase[2*HW_LO+off];
      a3 += wgt*depth_tx(dbase[off]);
    }
  }
  return make_float4(a0,a1,a2,a3);
}

// ---------------- weight prep (EXACT R10 layout): f32 -> f16, relayout + XOR-swizzle ----------------
// wbuf f16: [0,8192) w1 [oc64][kk128]; [8192,45056) w2 [oc64][kk576]; [45056,46208) w3 [2][576]; pad to 46592
__global__ __launch_bounds__(256) void k_wprep(const float* __restrict__ w1g,
    const float* __restrict__ w2g, const float* __restrict__ w3g, f16* __restrict__ wbuf){
  int i = blockIdx.x*256 + threadIdx.x;
  if (i >= 46592) return;
  float val = 0.0f;
  if (i < 8192){
    int oc = i>>7, kk = i&127, k = kk ^ ((oc&7)<<3);      // k = tap*8+ic, pad [72,128)=0
    if (k < 72) val = w1g[(oc*8 + (k&7))*9 + (k>>3)];
  } else if (i < 45056){
    int j = i - 8192; int oc = j/576, kk = j - oc*576, k = kk ^ ((oc&7)<<3); // k = tap*64+ic
    val = w2g[(oc*64 + (k&63))*9 + (k>>6)];
  } else {
    int j = i - 45056;
    if (j < 1152){ int nn = j/576, k = j - nn*576;
      val = w3g[(nn*64 + (k&63))*9 + (k>>6)];
    }
  }
  wbuf[i] = (f16)val;
}

// ---------------- k_pw: FB4 = bicubic prep (always); histB = mv-warp of histA, OOB -> FB (if doWarp) ----------------
__global__ __launch_bounds__(256) void k_pw(const float4* __restrict__ histA,
    const float* __restrict__ mv, const float* __restrict__ frame,
    const float* __restrict__ depth, const float* __restrict__ jit,
    float4* __restrict__ FB, float4* __restrict__ histB, int doWarp){
  int idx = blockIdx.x*256 + threadIdx.x;
  if (idx >= NB*HW_HI) return;
  int n = idx / HW_HI, p = idx - n*HW_HI;
  int y = p / W_HI, x = p - y*W_HI;
  const float* fbase = frame + (size_t)n*3*HW_LO;
  const float* dbase = depth + (size_t)n*HW_LO;
  float4 fb4 = fb_bicubic(fbase, dbase, jit[n*2], jit[n*2+1], x, y);
  FB[(size_t)n*HW_HI + p] = fb4;
  if (!doWarp) return;

  float cy = fmaxf(((float)y + 0.5f)/2.0f - 0.5f, 0.0f);
  float cx = fmaxf(((float)x + 0.5f)/2.0f - 0.5f, 0.0f);
  float y0f = floorf(cy), x0f = floorf(cx);
  float tyv = cy - y0f, txv = cx - x0f;
  int y0 = iclamp((int)y0f, 0, H_LO-1), y1 = iclamp((int)y0f+1, 0, H_LO-1);
  int x0 = iclamp((int)x0f, 0, W_LO-1), x1 = iclamp((int)x0f+1, 0, W_LO-1);
  const float* mb = mv + (size_t)n*HW_LO*2;
  float gx, gy;
  {
    float v00 = mb[(y0*W_LO+x0)*2], v01 = mb[(y0*W_LO+x1)*2];
    float v10 = mb[(y1*W_LO+x0)*2], v11 = mb[(y1*W_LO+x1)*2];
    float r0 = v00*(1.0f-tyv) + v10*tyv;
    float r1 = v01*(1.0f-tyv) + v11*tyv;
    gx = r0*(1.0f-txv) + r1*txv;
  }
  {
    float v00 = mb[(y0*W_LO+x0)*2+1], v01 = mb[(y0*W_LO+x1)*2+1];
    float v10 = mb[(y1*W_LO+x0)*2+1], v11 = mb[(y1*W_LO+x1)*2+1];
    float r0 = v00*(1.0f-tyv) + v10*tyv;
    float r1 = v01*(1.0f-tyv) + v11*tyv;
    gy = r0*(1.0f-txv) + r1*txv;
  }
  bool oob = (gx > 1.0f) || (gx < -1.0f) || (gy > 1.0f) || (gy < -1.0f);
  float4 res;
  if (oob) {
    res = fb4;   // same value as FB[n*HW+p] just computed
  } else {
    const float4* hb = histA + (size_t)n*HW_HI;
    float ix = ((gx + 1.0f)*(float)W_HI - 1.0f)*0.5f;
    float iy = ((gy + 1.0f)*(float)H_HI - 1.0f)*0.5f;
    float xf = floorf(ix), yf = floorf(iy);
    float tx = ix - xf, ty = iy - yf;
    int xi = (int)xf, yi = (int)yf;
    float wx[4], wy[4]; cubw(tx, wx); cubw(ty, wy);
    int xs[4], ys[4];
    #pragma unroll
    for (int j=0;j<4;j++){ xs[j]=iclamp(xi-1+j,0,W_HI-1); ys[j]=iclamp(yi-1+j,0,H_HI-1); }
    float a0=0.f,a1=0.f,a2=0.f,a3=0.f;
    #pragma unroll
    for (int i=0;i<4;i++){
      #pragma unroll
      for (int j=0;j<4;j++){
        float wgt = wy[i]*wx[j];
        float4 v = hb[ys[i]*W_HI + xs[j]];
        a0 += wgt*v.x; a1 += wgt*v.y; a2 += wgt*v.z; a3 += wgt*v.w;
      }
    }
    res = make_float4(a0,a1,a2,a3);
  }
  histB[(size_t)n*HW_HI + p] = res;
}

// ---------------- fused conv1+conv2+conv3 (R16 geometry + depth-2 weight prefetch) ----------------
__global__ __launch_bounds__(256,3) void k_fused(
    const float* __restrict__ frame, const float* __restrict__ depth,
    const float* __restrict__ jit, const float4* __restrict__ histIn,
    const float4* __restrict__ FB, const f16* __restrict__ wbuf,
    const float* __restrict__ b1g, const float* __restrict__ b2g, const float* __restrict__ b3g,
    float4* __restrict__ histOut, float* __restrict__ outp)
{
  __shared__ __attribute__((aligned(16))) char smem[LDS_BYTES];
  const int tid = threadIdx.x;
  const int wv = tid>>6, ln = tid&63, lr = ln&15, lq = ln>>4;
  const int n  = blockIdx.z;
  const int r0 = blockIdx.y * TILE;
  const int c0 = blockIdx.x * TILE;
  const float jx = jit[n*2], jy = jit[n*2+1];
  const int jix = (int)floorf(jx*2.0f), jiy = (int)floorf(jy*2.0f);
  const float* fbase = frame + (size_t)n*3*HW_LO;
  const float* dbase = depth + (size_t)n*HW_LO;
  const float4* hist4 = histIn + (size_t)n*HW_HI;
  const int wkk = (lr&7)<<3;     // weight k-swizzle key (oc&7 == lr&7)

  // prefetch conv1 weight fragments from global (latency hides under stage A)
  f16x8 B1[3][4];
  #pragma unroll
  for (int kc=0;kc<3;kc++)
    #pragma unroll
    for (int oct=0;oct<4;oct++){
      int oc = oct*16 + lr;
      int k0 = kc*32 + lq*8;
      B1[kc][oct] = *(const f16x8*)(wbuf + oc*128 + (k0 ^ wkk));
    }

  // ---- Stage A: cnn_in tile (20x20 px, 8ch) ----
  for (int e=tid; e<400; e+=256){
    int u = e/20, v = e - u*20;
    int cgy = iclamp(r0-3+u, 0, H_HI-1);
    int cgx = iclamp(c0-3+v, 0, W_HI-1);
    float v0=0.f, v1=0.f, v2=0.f, v3=0.f;
    int yy = cgy - jiy, xx = cgx - jix;
    if (yy>=0 && xx>=0 && !(yy&1) && !(xx&1)){
      int off = (yy>>1)*W_LO + (xx>>1);
      v0 = fbase[off]; v1 = fbase[HW_LO+off]; v2 = fbase[2*HW_LO+off];
      v3 = depth_tx(dbase[off]);
    }
    float4 h = hist4[cgy*W_HI + cgx];
    f16x8 pk;
    pk[0]=(f16)v0; pk[1]=(f16)v1; pk[2]=(f16)v2; pk[3]=(f16)v3;
    pk[4]=(f16)h.x; pk[5]=(f16)h.y; pk[6]=(f16)h.z; pk[7]=(f16)h.w;
    *(f16x8*)(smem + OFF_CNN + e*16) = pk;
  }
  __syncthreads();

  // ---- conv1: D[oc][m] over h1 grid 18x18 = 324 px (21 m-tiles: 6,5,5,5), K=96 (pad of 72) ----
  {
    float4 b1v[4];
    #pragma unroll
    for (int oct=0;oct<4;oct++) b1v[oct] = *(const float4*)(b1g + oct*16 + lq*4);
    const int nmt1 = (wv==0) ? 6 : 5;
    #pragma unroll
    for (int i=0;i<6;i++) if (i < nmt1){
      int tile = (i<5) ? (4*i + wv) : 20;
      int m = tile*16 + lr;
      int mc = imin(m, 323);
      int py = mc/18, px = mc - 18*py;
      int Ay = iclamp(r0-2+py, 0, H_HI-1);
      int Ax = iclamp(c0-2+px, 0, W_HI-1);
      f32x4 acc[4];
      #pragma unroll
      for (int oct=0;oct<4;oct++) acc[oct] = (f32x4){b1v[oct].x,b1v[oct].y,b1v[oct].z,b1v[oct].w};
      #pragma unroll
      for (int kc=0;kc<3;kc++){
        int k0 = kc*32 + lq*8;
        int t = imin(k0>>3, 8);
        int dy = (t*11)>>5; int dx = t - dy*3;
        int uu = iclamp(Ay+dy-1, 0, H_HI-1) - (r0-3);
        int vv = iclamp(Ax+dx-1, 0, W_HI-1) - (c0-3);
        f16x8 a = *(const f16x8*)(smem + OFF_CNN + (uu*20+vv)*16);
        #pragma unroll
        for (int oct=0;oct<4;oct++)
          acc[oct] = __builtin_amdgcn_mfma_f32_16x16x32_f16(B1[kc][oct], a, acc[oct], 0,0,0);
      }
      // h1 write (LDS swizzle): lane's pixel = m, oc = oct*16+lq*4+reg
      if (m < 324){
        #pragma unroll
        for (int oct=0;oct<4;oct++){
          f16x4 wv4;
          #pragma unroll
          for (int reg=0;reg<4;reg++) wv4[reg] = (f16)fmaxf(acc[oct][reg], 0.f);
          int oc0 = (oct*16 + lq*4) ^ ((px&7)<<3);
          *(f16x4*)(smem + OFF_H1 + ((m*64 + oc0)<<1)) = wv4;
        }
      }
    }
  }
  __syncthreads();

  // ---- conv2: D[oc][m] over h2 grid 16x16 = 256 px (16 m-tiles, 4/wave, balanced), K=576; depth-2 prefetch ----
  {
    const int mt0 = wv;  // tiles wv, 4+wv, 8+wv, 12+wv
    int rowOf[4][3], colc[4][3][2];
    #pragma unroll
    for (int mti=0;mti<4;mti++){
      int m = (mt0 + 4*mti)*16 + lr;       // < 256 always
      int py = m>>4, px = m&15;
      int Ay = iclamp(r0-1+py, 0, H_HI-1);
      int Ax = iclamp(c0-1+px, 0, W_HI-1);
      #pragma unroll
      for (int d=0;d<3;d++){
        rowOf[mti][d] = (iclamp(Ay+d-1, 0, H_HI-1) - (r0-2))*1152;  // *18*64
        int vv = iclamp(Ax+d-1, 0, W_HI-1) - (c0-2);
        int key = (vv&7)<<3;
        colc[mti][d][0] = vv*64 + ((lq*8) ^ key);
        colc[mti][d][1] = vv*64 + ((32+lq*8) ^ key);
      }
    }
    float4 b2v[4];
    #pragma unroll
    for (int oct=0;oct<4;oct++) b2v[oct] = *(const float4*)(b2g + oct*16 + lq*4);
    f32x4 acc2[4][4];
    #pragma unroll
    for (int mti=0;mti<4;mti++)
      #pragma unroll
      for (int oct=0;oct<4;oct++) acc2[mti][oct] = (f32x4){b2v[oct].x,b2v[oct].y,b2v[oct].z,b2v[oct].w};
    const f16* w2b = wbuf + 8192;   // [oc64][k576 swz]
    // prefetch kc=0 and kc=1 weight fragments (depth-2)
    f16x8 bf[4], bfn[4];
    #pragma unroll
    for (int oct=0;oct<4;oct++){
      bf[oct]  = *(const f16x8*)(w2b + (oct*16+lr)*576 + ((lq*8) ^ wkk));
      bfn[oct] = *(const f16x8*)(w2b + (oct*16+lr)*576 + ((32 + lq*8) ^ wkk));
    }
    #pragma unroll
    for (int kc=0;kc<18;kc++){
      const int tap = kc>>1, half = kc&1;
      const int dy = tap/3, dx = tap - dy*3;
      f16x8 bf2[4];
      if (kc < 16){
        const int kn = kc+2, tapn = kn>>1, halfn = kn&1;
        #pragma unroll
        for (int oct=0;oct<4;oct++)
          bf2[oct] = *(const f16x8*)(w2b + (oct*16+lr)*576 + ((tapn*64 + halfn*32 + lq*8) ^ wkk));
      }
      #pragma unroll
      for (int mti=0;mti<4;mti++){
        f16x8 a = *(const f16x8*)(smem + OFF_H1 + ((rowOf[mti][dy] + colc[mti][dx][half])<<1));
        #pragma unroll
        for (int oct=0;oct<4;oct++)
          acc2[mti][oct] = __builtin_amdgcn_mfma_f32_16x16x32_f16(bf[oct], a, acc2[mti][oct], 0,0,0);
      }
      #pragma unroll
      for (int oct=0;oct<4;oct++){ bf[oct] = bfn[oct]; bfn[oct] = bf2[oct]; }
    }
    __syncthreads();   // ALL waves done reading h1 before h2 overwrites it (h2 aliases h1)
    // h2 write (relu, LDS swizzle): m < 256 always, no guard
    #pragma unroll
    for (int mti=0;mti<4;mti++){
      int m = (mt0 + 4*mti)*16 + lr;
      int px = m&15;
      int base = m*64; int key = (px&7)<<3;
      #pragma unroll
      for (int oct=0;oct<4;oct++){
        f16x4 wv4;
        #pragma unroll
        for (int reg=0;reg<4;reg++) wv4[reg] = (f16)fmaxf(acc2[mti][oct][reg], 0.f);
        *(f16x4*)(smem + OFF_H2 + ((base + ((oct*16 + lq*4) ^ key))<<1)) = wv4;
      }
    }
  }
  __syncthreads();

  // ---- conv3: M=196 (14x14, 13 m-tiles: 4,3,3,3), N=2(pad 16), K=576; depth-2 prefetch ----
  {
    const int nm3 = (wv==0) ? 4 : 3;
    const int m3t[4] = {wv, 4+wv, 8+wv, 12};
    int rowOf[4][3], colc[4][3][2];
    #pragma unroll
    for (int i=0;i<4;i++){
      int m = imin(m3t[i]*16 + lr, 195);
      int py = m/14, px = m - 14*py;
      int Cy = iclamp(r0+py, 0, H_HI-1);
      int Cx = iclamp(c0+px, 0, W_HI-1);
      #pragma unroll
      for (int d=0;d<3;d++){
        rowOf[i][d] = (iclamp(Cy+d-1, 0, H_HI-1) - (r0-1))*1024;  // *16*64
        int vv = iclamp(Cx+d-1, 0, W_HI-1) - (c0-1);
        int key = (vv&7)<<3;
        colc[i][d][0] = vv*64 + ((lq*8) ^ key);
        colc[i][d][1] = vv*64 + ((32+lq*8) ^ key);
      }
    }
    f32x4 acc3[4] = {{0,0,0,0},{0,0,0,0},{0,0,0,0},{0,0,0,0}};
    const int cidx = ln&1;
    const f16* w3b = wbuf + 45056;
    f16x8 b  = *(const f16x8*)(w3b + cidx*576 + lq*8);
    f16x8 bn = *(const f16x8*)(w3b + cidx*576 + 32 + lq*8);
    #pragma unroll
    for (int kc=0;kc<18;kc++){
      const int tap = kc>>1, half = kc&1;
      const int dy = tap/3, dx = tap - dy*3;
      f16x8 bn2;
      if (kc < 16) bn2 = *(const f16x8*)(w3b + cidx*576 + (kc+2)*32 + lq*8);
      #pragma unroll
      for (int i=0;i<4;i++) if (i < nm3){
        f16x8 a = *(const f16x8*)(smem + OFF_H2 + ((rowOf[i][dy] + colc[i][dx][half])<<1));
        acc3[i] = __builtin_amdgcn_mfma_f32_16x16x32_f16(a, b, acc3[i], 0,0,0);
      }
      b = bn; bn = bn2;
    }
    // res region (41472+) does not overlap h2 (0..32768): no barrier needed before write
    float* sres = (float*)(smem + OFF_RES);
    if (lr < 2){
      float bv = b3g[lr];
      #pragma unroll
      for (int i=0;i<4;i++) if (i < nm3){
        #pragma unroll
        for (int reg=0;reg<4;reg++){
          int m = m3t[i]*16 + lq*4 + reg;
          if (m < 196) sres[lr*196 + m] = acc3[i][reg] + bv;
        }
      }
    }
  }
  __syncthreads();

  // ---- blend + outputs over 14x14 ----
  if (tid < 196){
    int ty = tid/14, tx = tid - 14*ty;
    int gy = r0 + ty, gx = c0 + tx;
    if (gy < H_HI && gx < W_HI){
      const float* sres = (const float*)(smem + OFF_RES);
      float a0 = sres[tid], a1 = sres[196+tid];
      float alpha = fminf(fmaxf(a0, 0.0f), 1.0f);
      int pix = gy*W_HI + gx;
      float4 fb = FB[(size_t)n*HW_HI + pix];
      float4 hv = hist4[pix];
      float h0 = hv.x*(1.0f-alpha) + fb.x*alpha;
      float h1 = hv.y*(1.0f-alpha) + fb.y*alpha;
      float h2 = hv.z*(1.0f-alpha) + fb.z*alpha;
      float h3 = hv.w*(1.0f-alpha) + fb.w*alpha + a1;
      h0 = fminf(fmaxf(h0,0.f),1.f); h1 = fminf(fmaxf(h1,0.f),1.f);
      h2 = fminf(fmaxf(h2,0.f),1.f); h3 = fminf(fmaxf(h3,0.f),1.f);
      histOut[(size_t)n*HW_HI + pix] = make_float4(h0,h1,h2,h3);
      float* rp = outp + (size_t)n*3*HW_HI + pix;
      rp[0] = h0; rp[HW_HI] = h1; rp[2*HW_HI] = h2;
    }
  }
}

extern "C" void kernel_launch(void* const* d_in, const int* in_sizes, int n_in,
                              void* d_out, int out_size, void* d_ws, size_t ws_size,
                              hipStream_t stream){
  const float* frames = (const float*)d_in[0];
  const float* depths = (const float*)d_in[1];
  const float* mvs    = (const float*)d_in[2];
  const float* jits   = (const float*)d_in[3];
  const float* w1 = (const float*)d_in[4];
  const float* b1 = (const float*)d_in[5];
  const float* w2 = (const float*)d_in[6];
  const float* b2 = (const float*)d_in[7];
  const float* w3 = (const float*)d_in[8];
  const float* b3 = (const float*)d_in[9];
  float* out = (float*)d_out;

  float4* FB4 = (float4*)d_ws;                     // [N][HW][4] f32 interleaved
  float4* HA  = FB4 + (size_t)NB*HW_HI;            // history ping
  float4* HB  = HA  + (size_t)NB*HW_HI;            // history pong
  f16*  wbuf = (f16*)(HB + (size_t)NB*HW_HI);      // 46592 f16 = 93184 B

  dim3 bs(256);
  int npix = NB*HW_HI;
  dim3 gpix((npix + 255)/256);
  dim3 gfused((W_HI + TILE-1)/TILE, (H_HI + TILE-1)/TILE, NB);

  k_wprep<<<dim3((46592+255)/256), bs, 0, stream>>>(w1, w2, w3, wbuf);

  for (int t = T_STEPS-1; t >= 0; --t){
    const float* fr = frames + (size_t)t*NB*3*HW_LO;
    const float* dp = depths + (size_t)t*NB*HW_LO;
    const float* mv = mvs    + (size_t)t*NB*HW_LO*2;
    const float* jt = jits   + (size_t)t*NB*2;
    float* ot = out + (size_t)t*NB*3*HW_HI;
    int doWarp = (t != T_STEPS-1) ? 1 : 0;

    k_pw<<<gpix, bs, 0, stream>>>(HA, mv, fr, dp, jt, FB4, HB, doWarp);
    const float4* histIn = doWarp ? (const float4*)HB : (const float4*)FB4;
    k_fused<<<gfused, bs, 0, stream>>>(fr, dp, jt, histIn, FB4, wbuf,
        b1, b2, b3, HA, ot);
  }
}